// Round 22
// baseline (30.018 us; speedup 1.0000x reference)
//
#include <hip/hip_runtime.h>
#include <hip/hip_bf16.h>

#define F 32
#define Dd 16
#define C 64
#define Kk 8
#define CLIPV (1.0f - 1e-6f)
#define K2 2.8853900817779268f  // 2*log2(e): tanh(z)=1-2/(2^(K2*z)+1)
#define NBLK 1024               // 1024 blocks x 128 rows = 131072
#define HALF 256                // ushorts per chunk per half: 32 rows * 8 bf16

typedef short v8s __attribute__((ext_vector_type(8)));
typedef float v4f __attribute__((ext_vector_type(4)));
typedef float v2f __attribute__((ext_vector_type(2)));

// bf16 pack via native casts: compiler fuses pairs into v_cvt_pk_bf16_f32
static __device__ inline unsigned pkbf(float lo, float hi) {
    const unsigned l = __bfloat16_as_ushort(__float2bfloat16(lo));
    const unsigned hh = __bfloat16_as_ushort(__float2bfloat16(hi));
    return l | (hh << 16);
}

// LDS-only barrier: wait own ds ops (lgkmcnt) then s_barrier; no vmcnt drain
// (X prefetches / output stores stay in flight across it).
#define BAR_LGKM() do {                                          \
    asm volatile("s_waitcnt lgkmcnt(0)" ::: "memory");           \
    __builtin_amdgcn_s_barrier();                                \
    asm volatile("" ::: "memory");                               \
} while (0)

// r22 = r21 + software-pipelined HALF-tiles (intra-wave pipe overlap):
//  - block owns 128 rows, processed as 4 half-tiles of 32 rows through TWO
//    16KB LDS buffers (total 32KB -> occupancy unchanged, 16 waves/CU).
//  - stage s (s=0..4): [eval half s -> buf s&1 (VALU)] and [mfma half s-1
//    from buf (s-1)&1 (LDS+MFMA)] sit in ONE basic block with no mutual
//    dependency -> scheduler interleaves them inside each wave; the VALU
//    convoy of pure-phase designs (r8/r12/r15 failures) is broken without
//    sacrificing LDS occupancy or needing cross-block luck.
//  - eval: thread (fe=tid&31, rg=tid>>5) owns feature fe, rows rg*4..+3 of
//    the half; Clenshaw table in VGPRs; shfl-deduped sincos (r21).
//  - mfma: wave wu owns classes [16wu,16wu+16); chunk-major swizzled basis
//    (slot=row^(fe&7)); bias via MFMA C-in; nontemporal X loads/out stores.
__global__ __launch_bounds__(256, 4) void qkan_kernel(
    const float* __restrict__ X,        // [B,32]
    const float* __restrict__ phases,   // [16]
    const float* __restrict__ lcu_w,    // [32,16]
    const float* __restrict__ sscale,   // [32]
    const float* __restrict__ sbias,    // [32]
    const float* __restrict__ coeff,    // [64,32,8]
    const float* __restrict__ kbias,    // [64]
    float* __restrict__ out)            // [B,64]
{
    __shared__ unsigned short s_basis[2][F * HALF];   // 2 x 16384 B = 32 KB

    const int tid = threadIdx.x;
    const int lane = tid & 63;
    const int wu = __builtin_amdgcn_readfirstlane(tid >> 6);
    const int h = lane >> 4;
    const int r16 = lane & 15;
    const int fe = tid & 31;   // eval feature
    const int fe7 = fe & 7;
    const int rg = tid >> 5;   // eval row-group (4 rows of the half)

    const int rb = blockIdx.x * 128;

    // ---- X prefetch for half 0 (nontemporal: stream-once) ----
    float xq[4], xn[4];
    {
        const float* xp = X + (size_t)(rb + rg * 4) * F + fe;
#pragma unroll
        for (int m = 0; m < 4; ++m) xq[m] = __builtin_nontemporal_load(xp + m * F);
    }

    // ---- one sincos per lane; pairs distributed by shfl in the fold ----
    float sp0, cp0;
    __sincosf(phases[lane & 15], &sp0, &cp0);

    // ---- fold Clenshaw table for feature fe into VGPRs ----
    // K2*z(x) = sum_d a_d T_d(x) + sqrt(1-x^2) * sum_d b_d U_{d-1}(x) + fbias
    v2f cc[16];
    float fbias;
    {
        const float* lwf = lcu_w + fe * Dd;
        float wv[16];
        float asum = 0.f;
#pragma unroll
        for (int d = 0; d < Dd; ++d) {
            wv[d] = lwf[d];
            asum += fabsf(wv[d]);
        }
        const float sc = K2 * sscale[fe] / (asum + 1e-6f);
#pragma unroll
        for (int d = 0; d < Dd; ++d) {
            const float cpd = __shfl(cp0, d, 16);
            const float spd = __shfl(sp0, d, 16);
            cc[d][0] = sc * wv[d] * cpd;    // a_{d+1}
            cc[d][1] = -sc * wv[d] * spd;   // b_{d+1}
        }
        fbias = K2 * sbias[fe];
    }

    // ---- B fragments: wave wu owns classes [16wu,16wu+16) ----
    // step q, lane quarter h, regs j hold kappa=(4q+h)*8+j (K-perm invariant)
    v8s Bfr[8];
    const int cidx = wu * 16 + r16;
#pragma unroll
    for (int q = 0; q < 8; ++q) {
        const float* gp = coeff + ((size_t)(cidx * F + 4 * q + h) * Kk);
        const float4 g0 = *reinterpret_cast<const float4*>(gp);
        const float4 g1 = *reinterpret_cast<const float4*>(gp + 4);
        union { unsigned u[4]; v8s v; } bb;
        bb.u[0] = pkbf(g0.x, g0.y);
        bb.u[1] = pkbf(g0.z, g0.w);
        bb.u[2] = pkbf(g1.x, g1.y);
        bb.u[3] = pkbf(g1.z, g1.w);
        Bfr[q] = bb.v;
    }
    const float biasreg = kbias[cidx];

#pragma unroll
    for (int s = 0; s < 5; ++s) {
        // ---- eval half s -> buf s&1 (stages 0..3) ----
        if (s < 4) {
            // prefetch next half's X first (stays in flight under the eval)
            if (s + 1 < 4) {
                const float* xp = X + (size_t)(rb + (s + 1) * 32 + rg * 4) * F + fe;
#pragma unroll
                for (int m = 0; m < 4; ++m)
                    xn[m] = __builtin_nontemporal_load(xp + m * F);
            }
            unsigned short* buf = s_basis[s & 1];
#pragma unroll
            for (int m = 0; m < 4; ++m) {
                const int row = rg * 4 + m;  // 0..31 within half
                const float x = __builtin_amdgcn_fmed3f(xq[m], -CLIPV, CLIPV);
                const float s1 = __builtin_amdgcn_sqrtf(__builtin_fmaf(-x, x, 1.f));
                const float tx = x + x;
                const v2f tx2 = {tx, tx};
                v2f w = {0.f, 0.f}, wp = {0.f, 0.f};
#pragma unroll
                for (int j = 15; j >= 0; --j) {
                    const v2f wn = __builtin_elementwise_fma(tx2, w, cc[j] - wp);
                    wp = w;
                    w = wn;
                }
                float z = fbias - wp[0];
                z = __builtin_fmaf(x, w[0], z);
                z = __builtin_fmaf(s1, w[1], z);
                const float e = __builtin_amdgcn_exp2f(z);
                const float rr = __builtin_amdgcn_rcpf(e + 1.f);
                const float t = __builtin_fmaf(-2.f, rr, 1.f);
                const float t2 = t + t;
                const float b1 = t;
                const float b2 = t2 * b1 - 1.f;
                const float b3 = t2 * b2 - b1;
                const float b4 = t2 * b3 - b2;
                const float b5 = t2 * b4 - b3;
                const float b6 = t2 * b5 - b4;
                const float b7 = t2 * b6 - b5;
                uint4 pk;
                pk.x = pkbf(1.f, b1);
                pk.y = pkbf(b2, b3);
                pk.z = pkbf(b4, b5);
                pk.w = pkbf(b6, b7);
                *reinterpret_cast<uint4*>(
                    &buf[fe * HALF + ((row ^ fe7) << 3)]) = pk;
            }
        }

        // ---- mfma half s-1 from buf (s-1)&1 (stages 1..4), independent of eval ----
        if (s >= 1) {
            const unsigned short* buf = s_basis[(s - 1) & 1];
            const int row_base = rb + (s - 1) * 32;
#pragma unroll
            for (int t = 0; t < 2; ++t) {
                const int s0 = ((t * 16 + r16) ^ h) << 3;
                v4f acc = {biasreg, biasreg, biasreg, biasreg};  // bias via C-in
#pragma unroll
                for (int q = 0; q < 8; ++q) {
                    const int idx = (4 * q + h) * HALF + (s0 ^ ((q & 1) << 5));
                    const v8s a = *reinterpret_cast<const v8s*>(&buf[idx]);
                    acc = __builtin_amdgcn_mfma_f32_16x16x32_bf16(a, Bfr[q], acc, 0, 0, 0);
                }
                const int row0 = row_base + t * 16 + h * 4;
#pragma unroll
                for (int i = 0; i < 4; ++i) {
                    __builtin_nontemporal_store(
                        acc[i], &out[(size_t)(row0 + i) * C + cidx]);
                }
            }
        }

        // ---- one LDS-only barrier per stage (none after the last) ----
        if (s < 4) {
            BAR_LGKM();
#pragma unroll
            for (int m = 0; m < 4; ++m) xq[m] = xn[m];
        }
    }
}

extern "C" void kernel_launch(void* const* d_in, const int* in_sizes, int n_in,
                              void* d_out, int out_size, void* d_ws, size_t ws_size,
                              hipStream_t stream) {
    const float* X  = (const float*)d_in[0];
    const float* ph = (const float*)d_in[1];
    const float* lw = (const float*)d_in[2];
    const float* ss = (const float*)d_in[3];
    const float* sb = (const float*)d_in[4];
    const float* kc = (const float*)d_in[5];
    const float* kb = (const float*)d_in[6];
    float* out = (float*)d_out;
    qkan_kernel<<<dim3(NBLK), dim3(256), 0, stream>>>(X, ph, lw, ss, sb, kc, kb, out);
}

// Round 23
// 24.752 us; speedup vs baseline: 1.2128x; 1.2128x over previous
//
#include <hip/hip_runtime.h>
#include <hip/hip_bf16.h>

#define F 32
#define Dd 16
#define C 64
#define Kk 8
#define CLIPV (1.0f - 1e-6f)
#define K2 2.8853900817779268f  // 2*log2(e): tanh(z)=1-2/(2^(K2*z)+1)
#define NBLK 1024
#define MT 2              // row-tiles of 64 per block

typedef short v8s __attribute__((ext_vector_type(8)));
typedef float v4f __attribute__((ext_vector_type(4)));
typedef float v2f __attribute__((ext_vector_type(2)));

// bf16 pack via native casts: compiler fuses pairs into v_cvt_pk_bf16_f32
static __device__ inline unsigned pkbf(float lo, float hi) {
    const unsigned l = __bfloat16_as_ushort(__float2bfloat16(lo));
    const unsigned hh = __bfloat16_as_ushort(__float2bfloat16(hi));
    return l | (hh << 16);
}

// LDS-only barriers: BAR_WRITES waits own ds_writes (lgkmcnt) then s_barrier;
// BAR_READS is a bare s_barrier (phase-2 ds_reads were all consumed by MFMAs).
// Neither drains vmcnt, so X prefetches / output stores stay in flight.
#define BAR_WRITES() do {                                        \
    asm volatile("s_waitcnt lgkmcnt(0)" ::: "memory");           \
    __builtin_amdgcn_s_barrier();                                \
    asm volatile("" ::: "memory");                               \
} while (0)
#define BAR_READS() do {                                         \
    asm volatile("" ::: "memory");                               \
    __builtin_amdgcn_s_barrier();                                \
    asm volatile("" ::: "memory");                               \
} while (0)

// FINAL (r21, measured best 24.86 us):
//  - phase-1 feature-major: thread (fe=tid&31, rg=tid>>5) evaluates feature fe
//    for rows rg*8..rg*8+7; folded Clenshaw table (33 coeffs) in VGPRs;
//    sincos(phases[d]) computed ONCE per lane (d=lane&15), distributed via
//    __shfl width-16; paired T/U Clenshaw via packed v2f fma; tanh in
//    exp2-domain (K2 pre-folded).
//  - basis LDS 32768 B exactly, XOR swizzle slot=row^(fe&7) (bank-clean on
//    both feature-major writes and row-major reads); 16 waves/CU.
//  - phase-2: wave wu owns classes [16wu,16wu+16), coeff fragments in VGPRs
//    (K-permuted f-major kappa=(4q+h)*8+j, same lane<->k map on A and B);
//    bias folded into MFMA C-in; nontemporal X loads / out stores.
__global__ __launch_bounds__(256, 4) void qkan_kernel(
    const float* __restrict__ X,        // [B,32]
    const float* __restrict__ phases,   // [16]
    const float* __restrict__ lcu_w,    // [32,16]
    const float* __restrict__ sscale,   // [32]
    const float* __restrict__ sbias,    // [32]
    const float* __restrict__ coeff,    // [64,32,8]
    const float* __restrict__ kbias,    // [64]
    float* __restrict__ out)            // [B,64]
{
    __shared__ unsigned short s_basis[F * 512];   // 32768 B exactly

    const int tid = threadIdx.x;
    const int lane = tid & 63;
    const int wu = __builtin_amdgcn_readfirstlane(tid >> 6);
    const int h = lane >> 4;
    const int r16 = lane & 15;
    const int fe = tid & 31;   // eval feature
    const int fe7 = fe & 7;
    const int rg = tid >> 5;   // eval row-group (8 rows)

    const int rb0 = blockIdx.x * (MT * 64);

    // ---- X prefetch for tile 0 (nontemporal: stream-once data) ----
    float xq[8];
    {
        const float* xp = X + (size_t)(rb0 + rg * 8) * F + fe;
#pragma unroll
        for (int m = 0; m < 8; ++m) xq[m] = __builtin_nontemporal_load(xp + m * F);
    }

    // ---- one sincos per lane; pairs distributed by shfl in the fold loop ----
    float sp0, cp0;
    __sincosf(phases[lane & 15], &sp0, &cp0);

    // ---- fold Clenshaw table for feature fe into VGPRs (once per kernel) ----
    // K2*z(x) = sum_d a_d T_d(x) + sqrt(1-x^2) * sum_d b_d U_{d-1}(x) + fbias
    v2f cc[16];
    float fbias;
    {
        const float* lwf = lcu_w + fe * Dd;
        float wv[16];
        float asum = 0.f;
#pragma unroll
        for (int d = 0; d < Dd; ++d) {
            wv[d] = lwf[d];
            asum += fabsf(wv[d]);
        }
        const float sc = K2 * sscale[fe] / (asum + 1e-6f);
#pragma unroll
        for (int d = 0; d < Dd; ++d) {
            const float cpd = __shfl(cp0, d, 16);
            const float spd = __shfl(sp0, d, 16);
            cc[d][0] = sc * wv[d] * cpd;    // a_{d+1}
            cc[d][1] = -sc * wv[d] * spd;   // b_{d+1}
        }
        fbias = K2 * sbias[fe];
    }

    // ---- B fragments: wave wu owns classes [16wu,16wu+16) ----
    // MFMA step q, lane quarter h, regs j hold phys kappa=(4q+h)*8+j,
    // i.e. f=4q+h, cheb-k=j (same lane<->k map on A and B => K-perm invariant)
    v8s Bfr[8];
    const int cidx = wu * 16 + r16;
#pragma unroll
    for (int q = 0; q < 8; ++q) {
        const float* gp = coeff + ((size_t)(cidx * F + 4 * q + h) * Kk);
        const float4 g0 = *reinterpret_cast<const float4*>(gp);
        const float4 g1 = *reinterpret_cast<const float4*>(gp + 4);
        union { unsigned u[4]; v8s v; } bb;
        bb.u[0] = pkbf(g0.x, g0.y);
        bb.u[1] = pkbf(g0.z, g0.w);
        bb.u[2] = pkbf(g1.x, g1.y);
        bb.u[3] = pkbf(g1.z, g1.w);
        Bfr[q] = bb.v;
    }
    const float biasreg = kbias[cidx];

    for (int mt = 0; mt < MT; ++mt) {
        const int row_base = rb0 + mt * 64;
        if (mt) BAR_READS();  // prev phase-2 LDS reads all consumed; no VMEM drain

        // prefetch next tile's X (stays in flight across the barriers)
        float xn[8];
        if (mt + 1 < MT) {
            const float* xp = X + (size_t)(row_base + 64 + rg * 8) * F + fe;
#pragma unroll
            for (int m = 0; m < 8; ++m) xn[m] = __builtin_nontemporal_load(xp + m * F);
        }

        // ---- phase 1: 8 independent row-evals of feature fe, table in VGPRs ----
        // swizzled write slot = row ^ fe7  (row = rg*8+m -> rg*8 + (m^fe7))
#pragma unroll
        for (int m = 0; m < 8; ++m) {
            const float x = __builtin_amdgcn_fmed3f(xq[m], -CLIPV, CLIPV);
            // 1 - x^2 >= ~1.9e-6 after the clip, so raw hardware sqrt is safe
            const float s1 = __builtin_amdgcn_sqrtf(__builtin_fmaf(-x, x, 1.f));
            const float tx = x + x;
            const v2f tx2 = {tx, tx};
            // paired Clenshaw (native packed fma): .x = T-chain, .y = U-chain
            v2f w = {0.f, 0.f}, wp = {0.f, 0.f};
#pragma unroll
            for (int j = 15; j >= 0; --j) {
                const v2f wn = __builtin_elementwise_fma(tx2, w, cc[j] - wp);
                wp = w;
                w = wn;
            }
            float z = fbias - wp[0];
            z = __builtin_fmaf(x, w[0], z);
            z = __builtin_fmaf(s1, w[1], z);
            // tanh via exp2 (K2 pre-folded): t = 1 - 2/(2^z + 1)
            const float e = __builtin_amdgcn_exp2f(z);
            const float rr = __builtin_amdgcn_rcpf(e + 1.f);
            const float t = __builtin_fmaf(-2.f, rr, 1.f);
            // Chebyshev basis T_0..T_7 -> one b128 LDS write (swizzled slot)
            const float t2 = t + t;
            const float b1 = t;
            const float b2 = t2 * b1 - 1.f;
            const float b3 = t2 * b2 - b1;
            const float b4 = t2 * b3 - b2;
            const float b5 = t2 * b4 - b3;
            const float b6 = t2 * b5 - b4;
            const float b7 = t2 * b6 - b5;
            uint4 pk;
            pk.x = pkbf(1.f, b1);
            pk.y = pkbf(b2, b3);
            pk.z = pkbf(b4, b5);
            pk.w = pkbf(b6, b7);
            *reinterpret_cast<uint4*>(
                &s_basis[fe * 512 + rg * 64 + ((m ^ fe7) << 3)]) = pk;
        }
        BAR_WRITES();  // lgkmcnt(0) only: writes visible; X/stores stay in flight

        // ---- phase 2: MFMA, wave wu computes classes [16wu,16wu+16) for 64 rows ----
        // read slot = (t*16+r16) ^ ((4q+h)&7) -> idx = ((v^h)<<3) ^ ((q&1)<<5)
#pragma unroll
        for (int t = 0; t < 4; ++t) {
            const int s0 = ((t * 16 + r16) ^ h) << 3;
            v4f acc = {biasreg, biasreg, biasreg, biasreg};  // bias via MFMA C-in
#pragma unroll
            for (int q = 0; q < 8; ++q) {
                const int idx = (4 * q + h) * 512 + (s0 ^ ((q & 1) << 5));
                const v8s a = *reinterpret_cast<const v8s*>(&s_basis[idx]);
                acc = __builtin_amdgcn_mfma_f32_16x16x32_bf16(a, Bfr[q], acc, 0, 0, 0);
            }
            const int row0 = row_base + t * 16 + h * 4;
#pragma unroll
            for (int i = 0; i < 4; ++i) {
                __builtin_nontemporal_store(acc[i], &out[(size_t)(row0 + i) * C + cidx]);
            }
        }

        if (mt + 1 < MT) {
#pragma unroll
            for (int m = 0; m < 8; ++m) xq[m] = xn[m];
        }
    }
}

extern "C" void kernel_launch(void* const* d_in, const int* in_sizes, int n_in,
                              void* d_out, int out_size, void* d_ws, size_t ws_size,
                              hipStream_t stream) {
    const float* X  = (const float*)d_in[0];
    const float* ph = (const float*)d_in[1];
    const float* lw = (const float*)d_in[2];
    const float* ss = (const float*)d_in[3];
    const float* sb = (const float*)d_in[4];
    const float* kc = (const float*)d_in[5];
    const float* kb = (const float*)d_in[6];
    float* out = (float*)d_out;
    qkan_kernel<<<dim3(NBLK), dim3(256), 0, stream>>>(X, ph, lw, ss, sb, kc, kb, out);
}